// Round 2
// baseline (3717.323 us; speedup 1.0000x reference)
//
#include <hip/hip_runtime.h>
#include <hip/hip_bf16.h>

#define N_NODES 50000
#define E_EDGES 800000
#define EN_EDGES 850000          // E + N self-loops
#define IN_F 128
#define H_HEADS 8
#define C_CH 32
#define HC 256                   // H*C
#define G_GRAPHS 64
#define NEG_SLOPE 0.2f

// monotonic float<->uint key for atomicMax on floats (handles negatives)
__device__ __forceinline__ unsigned fkey(float f) {
    unsigned u = __float_as_uint(f);
    return (u & 0x80000000u) ? ~u : (u | 0x80000000u);
}
__device__ __forceinline__ float finv(unsigned k) {
    unsigned u = (k & 0x80000000u) ? (k ^ 0x80000000u) : ~k;
    return __uint_as_float(u);
}

// h = x@W  [N,256]; a_src/a_dst = per-(node,head) attention logits.
// 8 nodes per block; 256 threads = one output column each.
__global__ __launch_bounds__(256) void k_gemm(const float* __restrict__ x,
        const float* __restrict__ W, const float* __restrict__ att_src,
        const float* __restrict__ att_dst, float* __restrict__ h,
        float* __restrict__ a_src, float* __restrict__ a_dst) {
    __shared__ float xs[8 * IN_F];
    const int n0 = blockIdx.x * 8;
    const int tid = threadIdx.x;
    // 8 rows = 1024 consecutive floats: coalesced float4 load
    ((float4*)xs)[tid] = ((const float4*)(x + (size_t)n0 * IN_F))[tid];
    __syncthreads();

    const int j = tid;            // output column 0..255
    float acc[8];
    #pragma unroll
    for (int r = 0; r < 8; ++r) acc[r] = 0.f;

    const float4* xs4 = (const float4*)xs;
    for (int k4 = 0; k4 < IN_F / 4; ++k4) {
        const float w0 = W[(k4 * 4 + 0) * HC + j];
        const float w1 = W[(k4 * 4 + 1) * HC + j];
        const float w2 = W[(k4 * 4 + 2) * HC + j];
        const float w3 = W[(k4 * 4 + 3) * HC + j];
        #pragma unroll
        for (int r = 0; r < 8; ++r) {
            float4 xv = xs4[r * (IN_F / 4) + k4];
            acc[r] += xv.x * w0 + xv.y * w1 + xv.z * w2 + xv.w * w3;
        }
    }

    const float asv = att_src[j], adv = att_dst[j];
    const int hh = j >> 5;
    #pragma unroll
    for (int r = 0; r < 8; ++r) {
        h[(size_t)(n0 + r) * HC + j] = acc[r];
        float s = acc[r] * asv, d = acc[r] * adv;
        #pragma unroll
        for (int off = 16; off; off >>= 1) {   // reduce within each 32-lane head group
            s += __shfl_xor(s, off, 64);
            d += __shfl_xor(d, off, 64);
        }
        if ((tid & 31) == 0) {
            a_src[(n0 + r) * H_HEADS + hh] = s;
            a_dst[(n0 + r) * H_HEADS + hh] = d;
        }
    }
}

// Pass A: segment max per (dst, head). One thread per edge, float4 logit loads.
__global__ __launch_bounds__(256) void k_edge_max(const int* __restrict__ ei,
        const float* __restrict__ a_src, const float* __restrict__ a_dst,
        unsigned* __restrict__ mkey) {
    int i = blockIdx.x * 256 + threadIdx.x;
    if (i >= EN_EDGES) return;
    int src, dst;
    if (i < E_EDGES) { src = ei[i]; dst = ei[E_EDGES + i]; }
    else             { src = dst = i - E_EDGES; }
    float4 s0 = ((const float4*)(a_src + src * H_HEADS))[0];
    float4 s1 = ((const float4*)(a_src + src * H_HEADS))[1];
    float4 d0 = ((const float4*)(a_dst + dst * H_HEADS))[0];
    float4 d1 = ((const float4*)(a_dst + dst * H_HEADS))[1];
    float e[8] = { s0.x + d0.x, s0.y + d0.y, s0.z + d0.z, s0.w + d0.w,
                   s1.x + d1.x, s1.y + d1.y, s1.z + d1.z, s1.w + d1.w };
    unsigned* mk = mkey + dst * H_HEADS;
    #pragma unroll
    for (int hh = 0; hh < 8; ++hh) {
        float v = e[hh] > 0.f ? e[hh] : NEG_SLOPE * e[hh];
        atomicMax(mk + hh, fkey(v));
    }
}

// Pass B: w = exp(e - m); denom += w; outacc[dst,:] += w * h[src,:]
// 4 edges per 256-thread block; one 64-lane wave per edge; lane l covers
// channels 4l..4l+3 (head = l>>3) with a float4 load of h[src].
__global__ __launch_bounds__(256) void k_edge_acc(const int* __restrict__ ei,
        const float* __restrict__ a_src, const float* __restrict__ a_dst,
        const unsigned* __restrict__ mkey, const float* __restrict__ h,
        float* __restrict__ denom, float* __restrict__ outacc) {
    const int wave = threadIdx.x >> 6;          // 0..3
    const int lane = threadIdx.x & 63;
    const int i = blockIdx.x * 4 + wave;
    if (i >= EN_EDGES) return;
    int src, dst;
    if (i < E_EDGES) { src = ei[i]; dst = ei[E_EDGES + i]; }
    else             { src = dst = i - E_EDGES; }
    const int hh = lane >> 3;                   // head for this lane's channels
    float e = a_src[src * H_HEADS + hh] + a_dst[dst * H_HEADS + hh];
    e = e > 0.f ? e : NEG_SLOPE * e;
    float m = finv(mkey[dst * H_HEADS + hh]);
    float w = __expf(e - m);
    if ((lane & 7) == 0) atomicAdd(denom + dst * H_HEADS + hh, w);
    float4 hv = ((const float4*)(h + (size_t)src * HC))[lane];
    float* oa = outacc + (size_t)dst * HC + lane * 4;
    atomicAdd(oa + 0, w * hv.x);
    atomicAdd(oa + 1, w * hv.y);
    atomicAdd(oa + 2, w * hv.z);
    atomicAdd(oa + 3, w * hv.w);
}

// Pass C: per (node, c): mean over heads of outacc/denom, +bias, relu,
// then atomic accumulate into per-graph pool + count.
__global__ __launch_bounds__(256) void k_node_out(const float* __restrict__ outacc,
        const float* __restrict__ denom, const float* __restrict__ bias,
        const int* __restrict__ batch, float* __restrict__ pool,
        float* __restrict__ cnt) {
    int idx = blockIdx.x * 256 + threadIdx.x;   // over N*C
    if (idx >= N_NODES * C_CH) return;
    int n = idx >> 5, c = idx & 31;
    float s = 0.f;
    #pragma unroll
    for (int hh = 0; hh < H_HEADS; ++hh)
        s += outacc[(size_t)n * HC + hh * C_CH + c]
             / (denom[n * H_HEADS + hh] + 1e-16f);
    s = s * (1.f / H_HEADS) + bias[c];
    s = s > 0.f ? s : 0.f;                      // relu
    int g = batch[n];
    atomicAdd(pool + g * C_CH + c, s);
    if (c == 0) atomicAdd(cnt + g, 1.f);
}

// Final: pooled mean + [G,2] linear; writes x_t then pooled into d_out.
__global__ __launch_bounds__(256) void k_final(const float* __restrict__ pool,
        const float* __restrict__ cnt, const float* __restrict__ lin_w,
        const float* __restrict__ lin_b, float* __restrict__ out) {
    __shared__ float pd[G_GRAPHS * C_CH];
    int t = threadIdx.x;
    for (int i = t; i < G_GRAPHS * C_CH; i += 256) {
        int g = i >> 5;
        float p = pool[i] / fmaxf(cnt[g], 1.f);
        pd[i] = p;
        out[G_GRAPHS * 2 + i] = p;              // pooled output (tuple elem 2)
    }
    __syncthreads();
    if (t < G_GRAPHS * 2) {
        int g = t >> 1, o = t & 1;
        float s = lin_b[o];
        #pragma unroll
        for (int c = 0; c < C_CH; ++c) s += pd[g * C_CH + c] * lin_w[c * 2 + o];
        out[t] = s;                             // x_t output (tuple elem 1)
    }
}

extern "C" void kernel_launch(void* const* d_in, const int* in_sizes, int n_in,
                              void* d_out, int out_size, void* d_ws, size_t ws_size,
                              hipStream_t stream) {
    const float* x       = (const float*)d_in[0];
    const int*   ei      = (const int*)d_in[1];
    const int*   batch   = (const int*)d_in[2];
    const float* W       = (const float*)d_in[3];
    const float* att_src = (const float*)d_in[4];
    const float* att_dst = (const float*)d_in[5];
    const float* bias    = (const float*)d_in[6];
    const float* lin_w   = (const float*)d_in[7];
    const float* lin_b   = (const float*)d_in[8];

    char* ws = (char*)d_ws;
    // layout (bytes):
    float*    h      = (float*)(ws);                 // 51,200,000
    float*    outacc = (float*)(ws + 51200000);      // 51,200,000
    float*    a_src  = (float*)(ws + 102400000);     //  1,600,000
    float*    a_dst  = (float*)(ws + 104000000);     //  1,600,000
    unsigned* mkey   = (unsigned*)(ws + 105600000);  //  1,600,000
    float*    denom  = (float*)(ws + 107200000);     //  1,600,000
    float*    pool   = (float*)(ws + 108800000);     //      8,192
    float*    cnt    = (float*)(ws + 108808192);     //        256
    // total ~108.8 MB

    hipMemsetAsync(outacc, 0, 51200000, stream);
    hipMemsetAsync(mkey,   0, 1600000, stream);
    hipMemsetAsync(denom,  0, 1600000, stream);
    hipMemsetAsync(pool,   0, 8192 + 256, stream);   // pool + cnt contiguous

    k_gemm<<<N_NODES / 8, 256, 0, stream>>>(x, W, att_src, att_dst, h, a_src, a_dst);
    k_edge_max<<<(EN_EDGES + 255) / 256, 256, 0, stream>>>(ei, a_src, a_dst, mkey);
    k_edge_acc<<<(EN_EDGES + 3) / 4, 256, 0, stream>>>(
        ei, a_src, a_dst, mkey, h, denom, outacc);
    k_node_out<<<(N_NODES * C_CH + 255) / 256, 256, 0, stream>>>(
        outacc, denom, bias, batch, pool, cnt);
    k_final<<<1, 256, 0, stream>>>(pool, cnt, lin_w, lin_b, (float*)d_out);
}

// Round 4
// 817.745 us; speedup vs baseline: 4.5458x; 4.5458x over previous
//
#include <hip/hip_runtime.h>
#include <hip/hip_bf16.h>

#define N_NODES 50000
#define E_EDGES 800000
#define IN_F 128
#define H_HEADS 8
#define C_CH 32
#define HC 256                   // H*C
#define G_GRAPHS 64
#define NEG_SLOPE 0.2f

// h = x@W  [N,256]; a_src/a_dst = per-(node,head) attention logits.
// 8 nodes per block; 256 threads = one output column each.
__global__ __launch_bounds__(256) void k_gemm(const float* __restrict__ x,
        const float* __restrict__ W, const float* __restrict__ att_src,
        const float* __restrict__ att_dst, float* __restrict__ h,
        float* __restrict__ a_src, float* __restrict__ a_dst) {
    __shared__ float xs[8 * IN_F];
    const int n0 = blockIdx.x * 8;
    const int tid = threadIdx.x;
    ((float4*)xs)[tid] = ((const float4*)(x + (size_t)n0 * IN_F))[tid];
    __syncthreads();

    const int j = tid;            // output column 0..255
    float acc[8];
    #pragma unroll
    for (int r = 0; r < 8; ++r) acc[r] = 0.f;

    const float4* xs4 = (const float4*)xs;
    for (int k4 = 0; k4 < IN_F / 4; ++k4) {
        const float w0 = W[(k4 * 4 + 0) * HC + j];
        const float w1 = W[(k4 * 4 + 1) * HC + j];
        const float w2 = W[(k4 * 4 + 2) * HC + j];
        const float w3 = W[(k4 * 4 + 3) * HC + j];
        #pragma unroll
        for (int r = 0; r < 8; ++r) {
            float4 xv = xs4[r * (IN_F / 4) + k4];
            acc[r] += xv.x * w0 + xv.y * w1 + xv.z * w2 + xv.w * w3;
        }
    }

    const float asv = att_src[j], adv = att_dst[j];
    const int hh = j >> 5;
    #pragma unroll
    for (int r = 0; r < 8; ++r) {
        h[(size_t)(n0 + r) * HC + j] = acc[r];
        float s = acc[r] * asv, d = acc[r] * adv;
        #pragma unroll
        for (int off = 16; off; off >>= 1) {   // reduce within each 32-lane head group
            s += __shfl_xor(s, off, 64);
            d += __shfl_xor(d, off, 64);
        }
        if ((tid & 31) == 0) {
            a_src[(n0 + r) * H_HEADS + hh] = s;
            a_dst[(n0 + r) * H_HEADS + hh] = d;
        }
    }
}

// in-degree histogram over real edges (self-loops handled in k_node)
__global__ __launch_bounds__(256) void k_hist(const int* __restrict__ ei,
        int* __restrict__ deg) {
    int i = blockIdx.x * 256 + threadIdx.x;
    if (i < E_EDGES) atomicAdd(deg + ei[E_EDGES + i], 1);
}

// single-block exclusive scan of deg[0..N) -> off, cursor; off[N]=E
__global__ __launch_bounds__(1024) void k_scan(const int* __restrict__ deg,
        int* __restrict__ off, int* __restrict__ cursor) {
    __shared__ int carry;
    __shared__ int wsum[16];
    const int tid = threadIdx.x, lane = tid & 63, wid = tid >> 6;
    if (tid == 0) carry = 0;
    __syncthreads();
    for (int base = 0; base < N_NODES; base += 1024) {
        int i = base + tid;
        int v = (i < N_NODES) ? deg[i] : 0;
        int s = v;
        #pragma unroll
        for (int d = 1; d < 64; d <<= 1) {
            int t = __shfl_up(s, d, 64);
            if (lane >= d) s += t;
        }
        if (lane == 63) wsum[wid] = s;
        __syncthreads();
        if (wid == 0 && lane < 16) {
            int t = wsum[lane];
            #pragma unroll
            for (int d = 1; d < 16; d <<= 1) {
                int u = __shfl_up(t, d, 64);
                if (lane >= d) t += u;
            }
            wsum[lane] = t;
        }
        __syncthreads();
        int wpre = wid ? wsum[wid - 1] : 0;
        int excl = carry + wpre + s - v;
        if (i < N_NODES) { off[i] = excl; cursor[i] = excl; }
        __syncthreads();
        if (tid == 0) carry += wsum[15];
        __syncthreads();
    }
    if (tid == 0) off[N_NODES] = E_EDGES;
}

// scatter src indices into CSR-by-dst
__global__ __launch_bounds__(256) void k_scatter(const int* __restrict__ ei,
        int* __restrict__ cursor, int* __restrict__ csr_src) {
    int i = blockIdx.x * 256 + threadIdx.x;
    if (i >= E_EDGES) return;
    int dst = ei[E_EDGES + i];
    int p = atomicAdd(cursor + dst, 1);
    csr_src[p] = ei[i];
}

// One 64-lane wave per destination node. Lane l: head hh=l>>3, channels
// 4*(l&7)..+3 of that head. Two passes over in-edges (max, then exp-acc),
// self-loop inline. Gather of h[src] is a full coalesced 1KB row per wave.
// Pass 2 processes two edges per iteration so two row-gathers are in flight.
__global__ __launch_bounds__(256) void k_node(const float* __restrict__ h,
        const float* __restrict__ a_src, const float* __restrict__ a_dst,
        const int* __restrict__ off, const int* __restrict__ csr_src,
        const int* __restrict__ batch, const float* __restrict__ bias,
        float* __restrict__ pool, float* __restrict__ cnt) {
    const int wave = threadIdx.x >> 6, lane = threadIdx.x & 63;
    const int n = blockIdx.x * 4 + wave;
    if (n >= N_NODES) return;
    const int hh = lane >> 3;
    const int beg = off[n], end = off[n + 1];
    const float adst = a_dst[n * H_HEADS + hh];
    float es = a_src[n * H_HEADS + hh] + adst;
    const float e_self = es > 0.f ? es : NEG_SLOPE * es;

    // pass 1: segment max (all lanes of a head group compute identically)
    float m = e_self;
    for (int k = beg; k < end; ++k) {
        int src = csr_src[k];
        float e = a_src[src * H_HEADS + hh] + adst;
        e = e > 0.f ? e : NEG_SLOPE * e;
        m = fmaxf(m, e);
    }

    // pass 2: denom + weighted gather-accumulate (2 edges / iter)
    float denom = 0.f;
    float4 acc = {0.f, 0.f, 0.f, 0.f};
    {
        float w = __expf(e_self - m);
        denom += w;
        float4 hv = ((const float4*)(h + (size_t)n * HC))[lane];
        acc.x += w * hv.x; acc.y += w * hv.y;
        acc.z += w * hv.z; acc.w += w * hv.w;
    }
    int k = beg;
    for (; k + 1 < end; k += 2) {
        int s0 = csr_src[k], s1 = csr_src[k + 1];
        float e0 = a_src[s0 * H_HEADS + hh] + adst;
        float e1 = a_src[s1 * H_HEADS + hh] + adst;
        e0 = e0 > 0.f ? e0 : NEG_SLOPE * e0;
        e1 = e1 > 0.f ? e1 : NEG_SLOPE * e1;
        float w0 = __expf(e0 - m);
        float w1 = __expf(e1 - m);
        float4 h0 = ((const float4*)(h + (size_t)s0 * HC))[lane];
        float4 h1 = ((const float4*)(h + (size_t)s1 * HC))[lane];
        denom += w0 + w1;
        acc.x += w0 * h0.x + w1 * h1.x;
        acc.y += w0 * h0.y + w1 * h1.y;
        acc.z += w0 * h0.z + w1 * h1.z;
        acc.w += w0 * h0.w + w1 * h1.w;
    }
    if (k < end) {
        int s0 = csr_src[k];
        float e0 = a_src[s0 * H_HEADS + hh] + adst;
        e0 = e0 > 0.f ? e0 : NEG_SLOPE * e0;
        float w0 = __expf(e0 - m);
        float4 h0 = ((const float4*)(h + (size_t)s0 * HC))[lane];
        denom += w0;
        acc.x += w0 * h0.x; acc.y += w0 * h0.y;
        acc.z += w0 * h0.z; acc.w += w0 * h0.w;
    }

    const float inv = 1.f / (denom + 1e-16f);
    float4 r = {acc.x * inv, acc.y * inv, acc.z * inv, acc.w * inv};
    // head mean: reduce across the 8 lanes sharing (lane&7)
    #pragma unroll
    for (int o = 8; o < 64; o <<= 1) {
        r.x += __shfl_xor(r.x, o, 64);
        r.y += __shfl_xor(r.y, o, 64);
        r.z += __shfl_xor(r.z, o, 64);
        r.w += __shfl_xor(r.w, o, 64);
    }
    if (lane < 8) {
        const int c0 = lane * 4;
        const int g = batch[n];
        float o0 = fmaxf(r.x * 0.125f + bias[c0 + 0], 0.f);
        float o1 = fmaxf(r.y * 0.125f + bias[c0 + 1], 0.f);
        float o2 = fmaxf(r.z * 0.125f + bias[c0 + 2], 0.f);
        float o3 = fmaxf(r.w * 0.125f + bias[c0 + 3], 0.f);
        float* pg = pool + g * C_CH + c0;
        atomicAdd(pg + 0, o0); atomicAdd(pg + 1, o1);
        atomicAdd(pg + 2, o2); atomicAdd(pg + 3, o3);
        if (lane == 0) atomicAdd(cnt + g, 1.f);
    }
}

// Final: pooled mean + [G,2] linear; writes x_t then pooled into d_out.
__global__ __launch_bounds__(256) void k_final(const float* __restrict__ pool,
        const float* __restrict__ cnt, const float* __restrict__ lin_w,
        const float* __restrict__ lin_b, float* __restrict__ out) {
    __shared__ float pd[G_GRAPHS * C_CH];
    int t = threadIdx.x;
    for (int i = t; i < G_GRAPHS * C_CH; i += 256) {
        int g = i >> 5;
        float p = pool[i] / fmaxf(cnt[g], 1.f);
        pd[i] = p;
        out[G_GRAPHS * 2 + i] = p;              // pooled output (tuple elem 2)
    }
    __syncthreads();
    if (t < G_GRAPHS * 2) {
        int g = t >> 1, o = t & 1;
        float s = lin_b[o];
        #pragma unroll
        for (int c = 0; c < C_CH; ++c) s += pd[g * C_CH + c] * lin_w[c * 2 + o];
        out[t] = s;                             // x_t output (tuple elem 1)
    }
}

extern "C" void kernel_launch(void* const* d_in, const int* in_sizes, int n_in,
                              void* d_out, int out_size, void* d_ws, size_t ws_size,
                              hipStream_t stream) {
    const float* x       = (const float*)d_in[0];
    const int*   ei      = (const int*)d_in[1];
    const int*   batch   = (const int*)d_in[2];
    const float* W       = (const float*)d_in[3];
    const float* att_src = (const float*)d_in[4];
    const float* att_dst = (const float*)d_in[5];
    const float* bias    = (const float*)d_in[6];
    const float* lin_w   = (const float*)d_in[7];
    const float* lin_b   = (const float*)d_in[8];

    char* ws = (char*)d_ws;
    float* h       = (float*)(ws);                  // 51,200,000
    float* a_src   = (float*)(ws + 51200000);       //  1,600,000
    float* a_dst   = (float*)(ws + 52800000);       //  1,600,000
    int*   deg     = (int*)  (ws + 54400000);       //    200,000
    int*   off     = (int*)  (ws + 54600000);       //    200,064 (N+1)
    int*   cursor  = (int*)  (ws + 54800064);       //    200,000
    int*   csr_src = (int*)  (ws + 55000064);       //  3,200,000
    float* pool    = (float*)(ws + 58200064);       //      8,192
    float* cnt     = (float*)(ws + 58208256);       //        256
    // total ~58.2 MB

    hipMemsetAsync(deg, 0, 200000, stream);
    hipMemsetAsync(pool, 0, 8192 + 256, stream);    // pool + cnt contiguous

    k_gemm<<<N_NODES / 8, 256, 0, stream>>>(x, W, att_src, att_dst, h, a_src, a_dst);
    k_hist<<<(E_EDGES + 255) / 256, 256, 0, stream>>>(ei, deg);
    k_scan<<<1, 1024, 0, stream>>>(deg, off, cursor);
    k_scatter<<<(E_EDGES + 255) / 256, 256, 0, stream>>>(ei, cursor, csr_src);
    k_node<<<(N_NODES + 3) / 4, 256, 0, stream>>>(
        h, a_src, a_dst, off, csr_src, batch, bias, pool, cnt);
    k_final<<<1, 256, 0, stream>>>(pool, cnt, lin_w, lin_b, (float*)d_out);
}